// Round 7
// baseline (290.960 us; speedup 1.0000x reference)
//
#include <hip/hip_runtime.h>
#include <hip/hip_bf16.h>

#define N_NODES_C 100000
#define N_PAD_C   100096   // = 391 * 256, padded for k1 tiles
#define N_RELS_C  237
#define N_EDGES_C 500000
#define D 128

#define NBLK_HIST 128          // grid-stride histogram blocks (run first)
#define NBLK_REL  60           // ceil(237/4), 4 rel rows per 512-thr block
#define NBLK_GEMM 784          // 49 windows x 16 (392 tiles x 2 halves, 1 phantom)
#define GEMM0     (NBLK_HIST + NBLK_REL)   // 188: first GEMM block index

typedef __attribute__((ext_vector_type(8))) short short8;
typedef __attribute__((ext_vector_type(4))) float f32x4;

__device__ __forceinline__ ushort f2bf(float x) {
    union { float f; uint u; } v; v.f = x;
    uint r = v.u + 0x7FFFu + ((v.u >> 16) & 1u);   // RNE
    return (ushort)(r >> 16);
}
__device__ __forceinline__ float bf2f_hi(uint u) {  // bits already in high half
    union { uint u; float f; } v; v.u = u; return v.f;
}

// ============ K0: fuse weights + biasC + sConst + deg zeroing =============
__global__ void k_fuse_w(const float* __restrict__ W_ent, const float* __restrict__ W_rel,
                         const float* __restrict__ W_ent2,
                         const float* __restrict__ b_ent, const float* __restrict__ b_rel,
                         const float* __restrict__ b_ent2,
                         const float* __restrict__ a_w, const float* __restrict__ a_b,
                         float* __restrict__ WR, ushort* __restrict__ WfTb,
                         float* __restrict__ biasC, float* __restrict__ sConst,
                         int* __restrict__ deg) {
    int j = threadIdx.x;       // 0..127
    int k = blockIdx.x;        // 0..127
    int which = blockIdx.y;    // 0..3
    if (which == 0) {
        float acc = 0.f;
        for (int i = 0; i < D; ++i) acc += W_ent[k*D+i] * W_ent2[i*D+j];
        WfTb[j*D + k] = f2bf(acc);
    } else if (which == 1) {
        float acc = 0.f;
        for (int i = 0; i < D; ++i) acc += W_ent[k*D+i] * W_ent2[(D+i)*D+j];
        WfTb[(D+j)*D + k] = f2bf(acc);
    } else if (which == 2) {
        float acc = 0.f;
        for (int i = 0; i < D; ++i) acc += W_rel[k*D+i] * W_ent2[(2*D+i)*D+j];
        WR[k*D + j] = acc;
    } else if (k == 0) {
        __shared__ float red[128];
        float acc = b_ent2[j];
        for (int i = 0; i < D; ++i) {
            acc += b_ent[i] * (W_ent2[i*D+j] + W_ent2[(D+i)*D+j]);
            acc += b_rel[i] * W_ent2[(2*D+i)*D+j];
        }
        biasC[j] = acc;
        red[j] = acc * a_w[j];
        __syncthreads();
        for (int s = 64; s > 0; s >>= 1) { if (j < s) red[j] += red[j+s]; __syncthreads(); }
        if (j == 0) sConst[0] = red[0] + a_b[0];
    } else {
        // zero deg[] with the 127 otherwise-idle blocks (16256 threads)
        int idx = (k - 1) * 128 + j;
        for (int i = idx; i < N_NODES_C; i += 127 * 128) deg[i] = 0;
    }
}

// ============ K1-mega: MFMA node GEMM + rel table + histogram =============
// blocks [0,128): grid-stride histogram of trip[:,0] into deg (starts early)
// blocks [128,188): 4 rel rows each -> RmB (bf16) + sR
// blocks [188,972): GEMM half-blocks, BM=256 (8 waves x 32 rows), XCD-PAIRED:
//   g = blk-GEMM0; window of 16: half=(g>>3)&1, tile=(g>>4)*8+(g&7).
//   Tile t's two halves at g and g+8 -> same blk%8 -> same XCD -> the B-half's
//   ent reads hit that XCD's L2 (verified: FETCH 53.5 -> 28.8 MB in round 3).
//   BM=256 halves block count & staging/barrier overhead vs round 3, and each
//   B-fragment ds_read feeds TWO MFMAs (acc[2][8] per wave).
__global__ __launch_bounds__(512, 6) void k1_mega(const float* __restrict__ ent,
                                                  const ushort* __restrict__ WfTb,
                                                  const float* __restrict__ a_w,
                                                  const float* __restrict__ relE,
                                                  const float* __restrict__ WR,
                                                  const int* __restrict__ trip,
                                                  ushort* __restrict__ AnB,
                                                  ushort* __restrict__ BnB,
                                                  ushort* __restrict__ RmB,
                                                  float* __restrict__ sA,
                                                  float* __restrict__ sB,
                                                  float* __restrict__ sR,
                                                  int* __restrict__ deg,
                                                  int n_nodes) {
    __shared__ __align__(16) union {
        ushort wL[128*128];    // 32 KB GEMM weight tile
        float  red[512];       // rel reduction
    } sm;
    int tid = threadIdx.x;
    int blk = blockIdx.x;

    if (blk < NBLK_HIST) {
        // ---- histogram blocks ----
        for (int e = blk*512 + tid; e < N_EDGES_C; e += NBLK_HIST*512) {
            int s = trip[3*e];
            if ((unsigned)s < (unsigned)N_NODES_C) atomicAdd(&deg[s], 1);
        }
        return;
    }
    if (blk < GEMM0) {
        // ---- rel blocks: 4 rows each ----
        int sub = tid >> 7, j = tid & 127;
        int r = (blk - NBLK_HIST)*4 + sub;
        float acc = 0.f;
        if (r < N_RELS_C) {
            for (int k = 0; k < D; ++k) acc += relE[r*D+k] * WR[k*D+j];
            RmB[r*D + j] = f2bf(acc);
        }
        sm.red[tid] = acc * a_w[j];
        __syncthreads();
        for (int s = 64; s > 0; s >>= 1) {
            if (j < s) sm.red[sub*128 + j] += sm.red[sub*128 + j + s];
            __syncthreads();
        }
        if (j == 0 && r < N_RELS_C) sR[r] = sm.red[sub*128];
        return;
    }

    // ---- GEMM half-blocks: 256 rows x 128 cols (XCD-paired swizzle) ----
    int g    = blk - GEMM0;
    int half = (g >> 3) & 1;
    int tile = ((g >> 4) << 3) + (g & 7);   // 0..391 (391 fully masked)
    int m0   = tile * 256;

    int wave = tid >> 6, lane = tid & 63;
    int q = lane >> 4, c = lane & 15;

    // ---- prefetch this wave's entire A operand: 2 m-tiles x 4 chunks ----
    float4 e0[2][4], e1[2][4];
#pragma unroll
    for (int mt = 0; mt < 2; ++mt)
#pragma unroll
        for (int chunk = 0; chunk < 4; ++chunk) {
            e0[mt][chunk] = make_float4(0.f,0.f,0.f,0.f);
            e1[mt][chunk] = e0[mt][chunk];
        }
#pragma unroll
    for (int mt = 0; mt < 2; ++mt) {
        int row = m0 + wave*32 + mt*16 + c;
        if (row < n_nodes) {
            const float* ep = &ent[(size_t)row*D];
#pragma unroll
            for (int chunk = 0; chunk < 4; ++chunk) {
                int k16 = chunk*4 + q;
                e0[mt][chunk] = *(const float4*)(ep + (k16 << 3));
                e1[mt][chunk] = *(const float4*)(ep + (k16 << 3) + 4);
            }
        }
    }

    // ---- stage this half's 128x128 bf16 weights into LDS (swizzled) ----
#pragma unroll
    for (int u = 0; u < 4; ++u) {
        int f = u*512 + tid;          // 0..2047
        int r = f >> 4, k16 = f & 15;
        *(uint4*)&sm.wL[r*128 + ((k16 ^ (r & 15)) << 3)] =
            *(const uint4*)&WfTb[(half*128 + r)*128 + (k16 << 3)];
    }

    // convert prefetched A rows to bf16 fragments (loads long since landed)
    short8 a[2][4];
#pragma unroll
    for (int mt = 0; mt < 2; ++mt)
#pragma unroll
        for (int chunk = 0; chunk < 4; ++chunk) {
            short8 pk;
            pk[0]=(short)f2bf(e0[mt][chunk].x); pk[1]=(short)f2bf(e0[mt][chunk].y);
            pk[2]=(short)f2bf(e0[mt][chunk].z); pk[3]=(short)f2bf(e0[mt][chunk].w);
            pk[4]=(short)f2bf(e1[mt][chunk].x); pk[5]=(short)f2bf(e1[mt][chunk].y);
            pk[6]=(short)f2bf(e1[mt][chunk].z); pk[7]=(short)f2bf(e1[mt][chunk].w);
            a[mt][chunk] = pk;
        }
    __syncthreads();

    f32x4 acc[2][8];
#pragma unroll
    for (int mt = 0; mt < 2; ++mt)
#pragma unroll
        for (int nt = 0; nt < 8; ++nt) { f32x4 z = {0.f,0.f,0.f,0.f}; acc[mt][nt] = z; }

#pragma unroll
    for (int chunk = 0; chunk < 4; ++chunk) {
        int k16 = chunk*4 + q;
#pragma unroll
        for (int nt = 0; nt < 8; ++nt) {
            short8 b = *(const short8*)&sm.wL[(nt*16 + c)*128 + ((k16 ^ c) << 3)];
            acc[0][nt] = __builtin_amdgcn_mfma_f32_16x16x32_bf16(a[0][chunk], b, acc[0][nt], 0, 0, 0);
            acc[1][nt] = __builtin_amdgcn_mfma_f32_16x16x32_bf16(a[1][chunk], b, acc[1][nt], 0, 0, 0);
        }
    }

    float aw[8];
#pragma unroll
    for (int nt = 0; nt < 8; ++nt) aw[nt] = a_w[nt*16 + c];

    ushort* out  = half ? BnB : AnB;
    float*  sOut = half ? sB  : sA;

#pragma unroll
    for (int mt = 0; mt < 2; ++mt) {
#pragma unroll
        for (int reg = 0; reg < 4; ++reg) {
            int m = m0 + wave*32 + mt*16 + q*4 + reg;
            float pa = 0.f;
#pragma unroll
            for (int nt = 0; nt < 8; ++nt) pa += acc[mt][nt][reg] * aw[nt];
#pragma unroll
            for (int msk = 1; msk < 16; msk <<= 1) pa += __shfl_xor(pa, msk);
            if (m < n_nodes) {
                if (c == 0) sOut[m] = pa;
#pragma unroll
                for (int nt = 0; nt < 8; ++nt)
                    out[(size_t)m*D + nt*16 + c] = f2bf(acc[mt][nt][reg]);
            }
        }
    }
}

// ============ scan stage 1 (coalesced block-local scan) =============
__global__ void k_scan1(const int* __restrict__ deg, int* __restrict__ off,
                        int* __restrict__ bsum, int n) {
    __shared__ int s[1024];
    int i = blockIdx.x*1024 + threadIdx.x;
    int v = (i < n) ? deg[i] : 0;
    s[threadIdx.x] = v; __syncthreads();
    for (int d = 1; d < 1024; d <<= 1) {
        int t = (threadIdx.x >= d) ? s[threadIdx.x - d] : 0;
        __syncthreads();
        s[threadIdx.x] += t;
        __syncthreads();
    }
    if (i < n) off[i] = s[threadIdx.x] - v;          // exclusive, pre-block-offset
    if (threadIdx.x == 1023) bsum[blockIdx.x] = s[1023];
}

// ============ scan stages 2+3 merged: every block re-scans the 98 bsums ======
__global__ void k_scan23(int* __restrict__ off, int* __restrict__ cursor,
                         const int* __restrict__ bsum, int n, int nb, int total_edges) {
    __shared__ int s[128];
    int t = threadIdx.x;
    if (t < 128) s[t] = (t < nb) ? bsum[t] : 0;
    __syncthreads();
    for (int d = 1; d < 128; d <<= 1) {
        int u = (t < 128 && t >= d) ? s[t - d] : 0;
        __syncthreads();
        if (t < 128) s[t] += u;          // inclusive scan
        __syncthreads();
    }
    int add = (blockIdx.x > 0) ? s[blockIdx.x - 1] : 0;   // exclusive prefix
    int i = blockIdx.x*1024 + t;
    if (i < n) {
        int o = off[i] + add;
        off[i] = o;
        cursor[i] = o;
    }
    if (i == 0) off[n] = total_edges;
}

// ============ K2c: scatter (key, sB[dst]+sR[rel]) record into CSR slot ============
__global__ void k_edge_b(const int* __restrict__ trip, const float* __restrict__ sB,
                         const float* __restrict__ sR, int* __restrict__ cursor,
                         uint2* __restrict__ kb, int n_edges) {
    int e = blockIdx.x*256 + threadIdx.x;
    if (e >= n_edges) return;
    int s = trip[3*e], d = trip[3*e+1], r = trip[3*e+2];
    if ((unsigned)s >= (unsigned)N_NODES_C || (unsigned)d >= (unsigned)N_NODES_C ||
        (unsigned)r >= (unsigned)N_RELS_C) return;   // guard (matches hist)
    float v = sB[d] + sR[r];
    int p = atomicAdd(&cursor[s], 1);
    kb[p] = make_uint2((uint)(d | (r << 20)), __float_as_uint(v));
}

// ============ K3: single-pass node-major aggregation, masked unroll-4 =============
__global__ void k_aggregate(const int* __restrict__ off, const uint2* __restrict__ kb,
                            const ushort* __restrict__ AnB, const ushort* __restrict__ BnB,
                            const ushort* __restrict__ RmB, const float* __restrict__ biasC,
                            const float* __restrict__ sA, const float* __restrict__ sConst,
                            float* __restrict__ h, int n_nodes) {
    int g = threadIdx.x >> 4, lane = threadIdx.x & 15;
    int n = blockIdx.x*16 + g;
    if (n >= n_nodes) return;
    int o0 = off[n], o1 = off[n+1];
    int c = lane*8;
    float* hp = &h[(size_t)n*D + c];
    if (o0 == o1) {
        *(float4*)hp     = make_float4(0.f,0.f,0.f,0.f);
        *(float4*)(hp+4) = make_float4(0.f,0.f,0.f,0.f);
        return;
    }
    float t = sA[n] + sConst[0];
    float num[8];
#pragma unroll
    for (int i = 0; i < 8; ++i) num[i] = 0.f;
    float den = 0.f;

    for (int p = o0; p < o1; p += 4) {
        uint2 kv[4]; uint4 gB[4], gR[4]; float vmask[4];
#pragma unroll
        for (int u = 0; u < 4; ++u) {
            int q = p + u;
            vmask[u] = (q < o1) ? 1.f : 0.f;
            int pc = (q < o1) ? q : (o1 - 1);
            kv[u] = kb[pc];
        }
#pragma unroll
        for (int u = 0; u < 4; ++u) {
            gB[u] = *(const uint4*)&BnB[(size_t)(kv[u].x & 0xFFFFF)*D + c];
            gR[u] = *(const uint4*)&RmB[(size_t)(kv[u].x >> 20)*D + c];
        }
#pragma unroll
        for (int u = 0; u < 4; ++u) {
            float logit = t + __uint_as_float(kv[u].y);
            float l = logit > 0.f ? logit : 0.01f*logit;
            float b = vmask[u] * expf(l);
            den += b;
            const uint* bu = (const uint*)&gB[u];
            const uint* ru = (const uint*)&gR[u];
#pragma unroll
            for (int i = 0; i < 4; ++i) {
                num[2*i]   += b * (bf2f_hi(bu[i] << 16)         + bf2f_hi(ru[i] << 16));
                num[2*i+1] += b * (bf2f_hi(bu[i] & 0xFFFF0000u) + bf2f_hi(ru[i] & 0xFFFF0000u));
            }
        }
    }

    float inv = 1.f / den;
    uint4 araw = *(const uint4*)&AnB[(size_t)n*D + c];
    const uint* au = (const uint*)&araw;
    float4 bc0 = *(const float4*)&biasC[c];
    float4 bc1 = *(const float4*)&biasC[c+4];
    float4 o0v, o1v;
    o0v.x = bf2f_hi(au[0] << 16)         + bc0.x + num[0]*inv;
    o0v.y = bf2f_hi(au[0] & 0xFFFF0000u) + bc0.y + num[1]*inv;
    o0v.z = bf2f_hi(au[1] << 16)         + bc0.z + num[2]*inv;
    o0v.w = bf2f_hi(au[1] & 0xFFFF0000u) + bc0.w + num[3]*inv;
    o1v.x = bf2f_hi(au[2] << 16)         + bc1.x + num[4]*inv;
    o1v.y = bf2f_hi(au[2] & 0xFFFF0000u) + bc1.y + num[5]*inv;
    o1v.z = bf2f_hi(au[3] << 16)         + bc1.z + num[6]*inv;
    o1v.w = bf2f_hi(au[3] & 0xFFFF0000u) + bc1.w + num[7]*inv;
    *(float4*)hp     = o0v;
    *(float4*)(hp+4) = o1v;
}

extern "C" void kernel_launch(void* const* d_in, const int* in_sizes, int n_in,
                              void* d_out, int out_size, void* d_ws, size_t ws_size,
                              hipStream_t stream) {
    const int*   trip   = (const int*)  d_in[0];
    const float* ent    = (const float*)d_in[1];
    const float* relE   = (const float*)d_in[2];
    const float* W_ent  = (const float*)d_in[3];
    const float* b_ent  = (const float*)d_in[4];
    const float* W_rel  = (const float*)d_in[5];
    const float* b_rel  = (const float*)d_in[6];
    const float* W_ent2 = (const float*)d_in[7];
    const float* b_ent2 = (const float*)d_in[8];
    const float* a_w    = (const float*)d_in[9];
    const float* a_b    = (const float*)d_in[10];
    float* h = (float*)d_out;

    // Workspace: ~57 MB total — stays under the proven-safe 57.6 MB.
    char* ws = (char*)d_ws;
    size_t o = 0;
    auto alloc = [&](size_t bytes) { size_t p = o; o += (bytes + 255) & ~(size_t)255; return p; };
    float*  WR     = (float*) (ws + alloc(128*128*4));
    ushort* WfTb   = (ushort*)(ws + alloc(256*128*2));
    float*  biasC  = (float*) (ws + alloc(128*4));
    ushort* RmB    = (ushort*)(ws + alloc((size_t)N_RELS_C*128*2));
    float*  sR     = (float*) (ws + alloc(N_RELS_C*4));
    float*  sConst = (float*) (ws + alloc(4));
    float*  sA     = (float*) (ws + alloc((size_t)N_NODES_C*4));
    float*  sB     = (float*) (ws + alloc((size_t)N_NODES_C*4));
    int*    deg    = (int*)   (ws + alloc((size_t)N_NODES_C*4));
    int*    off    = (int*)   (ws + alloc(((size_t)N_NODES_C+1)*4));
    int*    cursor = (int*)   (ws + alloc((size_t)N_NODES_C*4));
    int*    bsum   = (int*)   (ws + alloc(128*4));
    uint2*  kb     = (uint2*) (ws + alloc((size_t)N_EDGES_C*8));
    ushort* BnB    = (ushort*)(ws + alloc((size_t)N_PAD_C*128*2));
    ushort* AnB    = (ushort*)(ws + alloc((size_t)N_PAD_C*128*2));

    // 6 dispatches — verified round-3 pipeline with BM=256 GEMM blocks.
    k_fuse_w<<<dim3(128,4), 128, 0, stream>>>(W_ent, W_rel, W_ent2, b_ent, b_rel, b_ent2,
                                              a_w, a_b, WR, WfTb, biasC, sConst, deg);
    k1_mega<<<GEMM0 + NBLK_GEMM, 512, 0, stream>>>(
        ent, WfTb, a_w, relE, WR, trip, AnB, BnB, RmB, sA, sB, sR, deg, N_NODES_C);
    int nb = (N_NODES_C + 1023)/1024;   // 98
    k_scan1<<<nb, 1024, 0, stream>>>(deg, off, bsum, N_NODES_C);
    k_scan23<<<nb, 1024, 0, stream>>>(off, cursor, bsum, N_NODES_C, nb, N_EDGES_C);
    k_edge_b<<<(N_EDGES_C+255)/256, 256, 0, stream>>>(trip, sB, sR, cursor, kb, N_EDGES_C);
    k_aggregate<<<(N_NODES_C+15)/16, 256, 0, stream>>>(off, kb, AnB, BnB, RmB, biasC,
                                                       sA, sConst, h, N_NODES_C);
}

// Round 8
// 219.979 us; speedup vs baseline: 1.3227x; 1.3227x over previous
//
#include <hip/hip_runtime.h>
#include <hip/hip_bf16.h>

#define N_NODES_C 100000
#define N_PAD_C   100096   // padded to multiple of 128 for k1 tiles
#define N_RELS_C  237
#define N_EDGES_C 500000
#define D 128

#define NBLK_HIST 128          // grid-stride histogram blocks (run first)
#define NBLK_REL  60           // ceil(237/4), 4 rel rows per 512-thr block
#define NBLK_GEMM 1568         // 98 windows x 16 (= 784 tiles x 2 halves, 2 phantom)
#define GEMM0     (NBLK_HIST + NBLK_REL)   // 188: first GEMM block index

typedef __attribute__((ext_vector_type(8))) short short8;
typedef __attribute__((ext_vector_type(4))) float f32x4;

__device__ __forceinline__ ushort f2bf(float x) {
    union { float f; uint u; } v; v.f = x;
    uint r = v.u + 0x7FFFu + ((v.u >> 16) & 1u);   // RNE
    return (ushort)(r >> 16);
}
__device__ __forceinline__ float bf2f_hi(uint u) {  // bits already in high half
    union { uint u; float f; } v; v.u = u; return v.f;
}

// ============ K0: fuse weights + biasC + sConst + deg zeroing =============
// grid (128,4) x 128 thr.
// y=0: WfTb[j][k]    = bf16(W_ent @ W_ent2[0:128])   (A path, transposed)
// y=1: WfTb[128+j][k]= bf16(W_ent @ W_ent2[128:256]) (B path)
// y=2: WR[k][j]      = W_rel @ W_ent2[256:384]
// y=3,k=0: biasC[j] + sConst reduction; y=3,k>0: zero deg[] (replaces memset)
__global__ void k_fuse_w(const float* __restrict__ W_ent, const float* __restrict__ W_rel,
                         const float* __restrict__ W_ent2,
                         const float* __restrict__ b_ent, const float* __restrict__ b_rel,
                         const float* __restrict__ b_ent2,
                         const float* __restrict__ a_w, const float* __restrict__ a_b,
                         float* __restrict__ WR, ushort* __restrict__ WfTb,
                         float* __restrict__ biasC, float* __restrict__ sConst,
                         int* __restrict__ deg) {
    int j = threadIdx.x;       // 0..127
    int k = blockIdx.x;        // 0..127
    int which = blockIdx.y;    // 0..3
    if (which == 0) {
        float acc = 0.f;
        for (int i = 0; i < D; ++i) acc += W_ent[k*D+i] * W_ent2[i*D+j];
        WfTb[j*D + k] = f2bf(acc);
    } else if (which == 1) {
        float acc = 0.f;
        for (int i = 0; i < D; ++i) acc += W_ent[k*D+i] * W_ent2[(D+i)*D+j];
        WfTb[(D+j)*D + k] = f2bf(acc);
    } else if (which == 2) {
        float acc = 0.f;
        for (int i = 0; i < D; ++i) acc += W_rel[k*D+i] * W_ent2[(2*D+i)*D+j];
        WR[k*D + j] = acc;
    } else if (k == 0) {
        __shared__ float red[128];
        float acc = b_ent2[j];
        for (int i = 0; i < D; ++i) {
            acc += b_ent[i] * (W_ent2[i*D+j] + W_ent2[(D+i)*D+j]);
            acc += b_rel[i] * W_ent2[(2*D+i)*D+j];
        }
        biasC[j] = acc;
        red[j] = acc * a_w[j];
        __syncthreads();
        for (int s = 64; s > 0; s >>= 1) { if (j < s) red[j] += red[j+s]; __syncthreads(); }
        if (j == 0) sConst[0] = red[0] + a_b[0];
    } else {
        // zero deg[] with the 127 otherwise-idle blocks (16256 threads)
        int idx = (k - 1) * 128 + j;
        for (int i = idx; i < N_NODES_C; i += 127 * 128) deg[i] = 0;
    }
}

// ============ K1-mega: MFMA node GEMM + rel table + histogram =============
// blocks [0,128): grid-stride histogram of trip[:,0] into deg (starts early)
// blocks [128,188): 4 rel rows each -> RmB (bf16) + sR
// blocks [188,1756): GEMM half-blocks, XCD-PAIRED (verified round 3: FETCH
//   53.5 -> 28.8 MB): g = blk-GEMM0; window of 16: half=(g>>3)&1,
//   tile=(g>>4)*8+(g&7). Tile t's two halves at g and g+8 -> same blk%8 ->
//   same XCD -> B-half's ent reads hit that XCD's L2.
//   128 rows x 128 cols per block, 32 KB LDS, full A prefetch, 36 VGPR
//   (round-7 BM=256 variant spilled to scratch: +225 MB HBM, 2.3x slower).
__global__ __launch_bounds__(512, 6) void k1_mega(const float* __restrict__ ent,
                                                  const ushort* __restrict__ WfTb,
                                                  const float* __restrict__ a_w,
                                                  const float* __restrict__ relE,
                                                  const float* __restrict__ WR,
                                                  const int* __restrict__ trip,
                                                  ushort* __restrict__ AnB,
                                                  ushort* __restrict__ BnB,
                                                  ushort* __restrict__ RmB,
                                                  float* __restrict__ sA,
                                                  float* __restrict__ sB,
                                                  float* __restrict__ sR,
                                                  int* __restrict__ deg,
                                                  int n_nodes) {
    __shared__ __align__(16) ushort wL[128*128];   // 32 KB (GEMM blocks)
    int tid = threadIdx.x;
    int blk = blockIdx.x;

    if (blk < NBLK_HIST) {
        // ---- histogram blocks ----
        for (int e = blk*512 + tid; e < N_EDGES_C; e += NBLK_HIST*512) {
            int s = trip[3*e];
            if ((unsigned)s < (unsigned)N_NODES_C) atomicAdd(&deg[s], 1);
        }
        return;
    }
    if (blk < GEMM0) {
        // ---- rel blocks: 4 rows each ----
        __shared__ float red[512];
        int sub = tid >> 7, j = tid & 127;
        int r = (blk - NBLK_HIST)*4 + sub;
        float acc = 0.f;
        if (r < N_RELS_C) {
            for (int k = 0; k < D; ++k) acc += relE[r*D+k] * WR[k*D+j];
            RmB[r*D + j] = f2bf(acc);
        }
        red[tid] = acc * a_w[j];
        __syncthreads();
        for (int s = 64; s > 0; s >>= 1) {
            if (j < s) red[sub*128 + j] += red[sub*128 + j + s];
            __syncthreads();
        }
        if (j == 0 && r < N_RELS_C) sR[r] = red[sub*128];
        return;
    }

    // ---- GEMM half-blocks (XCD-paired swizzle) ----
    int g    = blk - GEMM0;
    int half = (g >> 3) & 1;
    int tile = ((g >> 4) << 3) + (g & 7);   // 0..783 (782,783 fully masked)
    int m0   = tile * 128;

    int wave = tid >> 6, lane = tid & 63;
    int q = lane >> 4, c = lane & 15;

    // ---- prefetch this wave's entire A operand (4 chunks) ----
    int row = m0 + wave*16 + c;
    float4 e0[4], e1[4];
#pragma unroll
    for (int chunk = 0; chunk < 4; ++chunk) {
        e0[chunk] = make_float4(0.f,0.f,0.f,0.f);
        e1[chunk] = e0[chunk];
    }
    if (row < n_nodes) {
        const float* ep = &ent[(size_t)row*D];
#pragma unroll
        for (int chunk = 0; chunk < 4; ++chunk) {
            int k16 = chunk*4 + q;
            e0[chunk] = *(const float4*)(ep + (k16 << 3));
            e1[chunk] = *(const float4*)(ep + (k16 << 3) + 4);
        }
    }

    // ---- stage this half's 128x128 bf16 weights into LDS (swizzled) ----
#pragma unroll
    for (int u = 0; u < 4; ++u) {
        int f = u*512 + tid;          // 0..2047
        int r = f >> 4, k16 = f & 15;
        *(uint4*)&wL[r*128 + ((k16 ^ (r & 15)) << 3)] =
            *(const uint4*)&WfTb[(half*128 + r)*128 + (k16 << 3)];
    }

    // convert prefetched A rows to bf16 fragments (loads long since landed)
    short8 a[4];
#pragma unroll
    for (int chunk = 0; chunk < 4; ++chunk) {
        short8 pk;
        pk[0]=(short)f2bf(e0[chunk].x); pk[1]=(short)f2bf(e0[chunk].y);
        pk[2]=(short)f2bf(e0[chunk].z); pk[3]=(short)f2bf(e0[chunk].w);
        pk[4]=(short)f2bf(e1[chunk].x); pk[5]=(short)f2bf(e1[chunk].y);
        pk[6]=(short)f2bf(e1[chunk].z); pk[7]=(short)f2bf(e1[chunk].w);
        a[chunk] = pk;
    }
    __syncthreads();

    f32x4 acc[8];
#pragma unroll
    for (int nt = 0; nt < 8; ++nt) { f32x4 z = {0.f,0.f,0.f,0.f}; acc[nt] = z; }

#pragma unroll
    for (int chunk = 0; chunk < 4; ++chunk) {
        int k16 = chunk*4 + q;
#pragma unroll
        for (int nt = 0; nt < 8; ++nt) {
            int wrow = nt*16 + c;
            short8 b = *(const short8*)&wL[wrow*128 + ((k16 ^ c) << 3)];
            acc[nt] = __builtin_amdgcn_mfma_f32_16x16x32_bf16(a[chunk], b, acc[nt], 0, 0, 0);
        }
    }

    float aw[8];
#pragma unroll
    for (int nt = 0; nt < 8; ++nt) aw[nt] = a_w[nt*16 + c];

    ushort* out  = half ? BnB : AnB;
    float*  sOut = half ? sB  : sA;

#pragma unroll
    for (int reg = 0; reg < 4; ++reg) {
        int m = m0 + wave*16 + q*4 + reg;
        float pa = 0.f;
#pragma unroll
        for (int nt = 0; nt < 8; ++nt) pa += acc[nt][reg] * aw[nt];
#pragma unroll
        for (int msk = 1; msk < 16; msk <<= 1) pa += __shfl_xor(pa, msk);
        if (m < n_nodes) {
            if (c == 0) sOut[m] = pa;
#pragma unroll
            for (int nt = 0; nt < 8; ++nt)
                out[(size_t)m*D + nt*16 + c] = f2bf(acc[nt][reg]);
        }
    }
}

// ============ scan stage 1 (coalesced block-local scan) =============
__global__ void k_scan1(const int* __restrict__ deg, int* __restrict__ off,
                        int* __restrict__ bsum, int n) {
    __shared__ int s[1024];
    int i = blockIdx.x*1024 + threadIdx.x;
    int v = (i < n) ? deg[i] : 0;
    s[threadIdx.x] = v; __syncthreads();
    for (int d = 1; d < 1024; d <<= 1) {
        int t = (threadIdx.x >= d) ? s[threadIdx.x - d] : 0;
        __syncthreads();
        s[threadIdx.x] += t;
        __syncthreads();
    }
    if (i < n) off[i] = s[threadIdx.x] - v;          // exclusive, pre-block-offset
    if (threadIdx.x == 1023) bsum[blockIdx.x] = s[1023];
}

// ============ scan stages 2+3 merged: every block re-scans the 98 bsums ======
__global__ void k_scan23(int* __restrict__ off, int* __restrict__ cursor,
                         const int* __restrict__ bsum, int n, int nb, int total_edges) {
    __shared__ int s[128];
    int t = threadIdx.x;
    if (t < 128) s[t] = (t < nb) ? bsum[t] : 0;
    __syncthreads();
    for (int d = 1; d < 128; d <<= 1) {
        int u = (t < 128 && t >= d) ? s[t - d] : 0;
        __syncthreads();
        if (t < 128) s[t] += u;          // inclusive scan
        __syncthreads();
    }
    int add = (blockIdx.x > 0) ? s[blockIdx.x - 1] : 0;   // exclusive prefix
    int i = blockIdx.x*1024 + t;
    if (i < n) {
        int o = off[i] + add;
        off[i] = o;
        cursor[i] = o;
    }
    if (i == 0) off[n] = total_edges;
}

// ============ K2c: scatter (key, b_e) record into CSR slot ============
// NEW: computes the FULL edge coefficient b_e = exp(leaky(sA[s]+sB[d]+sR[r]+const))
// once per edge here (500K exps, 1 lane each), instead of 16 redundant lanes
// per edge in k_aggregate (12.8M exps). Same operand association as before:
// t = sA+sConst; v = sB+sR; logit = t+v  (bit-identical to prior split).
__global__ void k_edge_b(const int* __restrict__ trip, const float* __restrict__ sA,
                         const float* __restrict__ sB, const float* __restrict__ sR,
                         const float* __restrict__ sConst, int* __restrict__ cursor,
                         uint2* __restrict__ kb, int n_edges) {
    int e = blockIdx.x*256 + threadIdx.x;
    if (e >= n_edges) return;
    int s = trip[3*e], d = trip[3*e+1], r = trip[3*e+2];
    if ((unsigned)s >= (unsigned)N_NODES_C || (unsigned)d >= (unsigned)N_NODES_C ||
        (unsigned)r >= (unsigned)N_RELS_C) return;   // guard (matches hist)
    float v = sB[d] + sR[r];
    float t = sA[s] + sConst[0];
    float logit = t + v;
    float l = logit > 0.f ? logit : 0.01f*logit;
    float b = expf(l);
    int p = atomicAdd(&cursor[s], 1);
    kb[p] = make_uint2((uint)(d | (r << 20)), __float_as_uint(b));
}

// ============ K3: single-pass node-major aggregation, masked unroll-4 =============
// h[n] = An[n] + biasC + num/den; kb carries precomputed b_e, so the inner loop
// is pure load + FMA (no exp/leaky). 16 lanes per node (4 chains/wave).
__global__ void k_aggregate(const int* __restrict__ off, const uint2* __restrict__ kb,
                            const ushort* __restrict__ AnB, const ushort* __restrict__ BnB,
                            const ushort* __restrict__ RmB, const float* __restrict__ biasC,
                            float* __restrict__ h, int n_nodes) {
    int g = threadIdx.x >> 4, lane = threadIdx.x & 15;
    int n = blockIdx.x*16 + g;
    if (n >= n_nodes) return;
    int o0 = off[n], o1 = off[n+1];
    int c = lane*8;
    float* hp = &h[(size_t)n*D + c];
    if (o0 == o1) {
        *(float4*)hp     = make_float4(0.f,0.f,0.f,0.f);
        *(float4*)(hp+4) = make_float4(0.f,0.f,0.f,0.f);
        return;
    }
    float num[8];
#pragma unroll
    for (int i = 0; i < 8; ++i) num[i] = 0.f;
    float den = 0.f;

    for (int p = o0; p < o1; p += 4) {
        uint2 kv[4]; uint4 gB[4], gR[4]; float vmask[4];
#pragma unroll
        for (int u = 0; u < 4; ++u) {
            int q = p + u;
            vmask[u] = (q < o1) ? 1.f : 0.f;
            int pc = (q < o1) ? q : (o1 - 1);
            kv[u] = kb[pc];
        }
#pragma unroll
        for (int u = 0; u < 4; ++u) {
            gB[u] = *(const uint4*)&BnB[(size_t)(kv[u].x & 0xFFFFF)*D + c];
            gR[u] = *(const uint4*)&RmB[(size_t)(kv[u].x >> 20)*D + c];
        }
#pragma unroll
        for (int u = 0; u < 4; ++u) {
            float b = vmask[u] * __uint_as_float(kv[u].y);   // b_e precomputed
            den += b;
            const uint* bu = (const uint*)&gB[u];
            const uint* ru = (const uint*)&gR[u];
#pragma unroll
            for (int i = 0; i < 4; ++i) {
                num[2*i]   += b * (bf2f_hi(bu[i] << 16)         + bf2f_hi(ru[i] << 16));
                num[2*i+1] += b * (bf2f_hi(bu[i] & 0xFFFF0000u) + bf2f_hi(ru[i] & 0xFFFF0000u));
            }
        }
    }

    float inv = 1.f / den;
    uint4 araw = *(const uint4*)&AnB[(size_t)n*D + c];
    const uint* au = (const uint*)&araw;
    float4 bc0 = *(const float4*)&biasC[c];
    float4 bc1 = *(const float4*)&biasC[c+4];
    float4 o0v, o1v;
    o0v.x = bf2f_hi(au[0] << 16)         + bc0.x + num[0]*inv;
    o0v.y = bf2f_hi(au[0] & 0xFFFF0000u) + bc0.y + num[1]*inv;
    o0v.z = bf2f_hi(au[1] << 16)         + bc0.z + num[2]*inv;
    o0v.w = bf2f_hi(au[1] & 0xFFFF0000u) + bc0.w + num[3]*inv;
    o1v.x = bf2f_hi(au[2] << 16)         + bc1.x + num[4]*inv;
    o1v.y = bf2f_hi(au[2] & 0xFFFF0000u) + bc1.y + num[5]*inv;
    o1v.z = bf2f_hi(au[3] << 16)         + bc1.z + num[6]*inv;
    o1v.w = bf2f_hi(au[3] & 0xFFFF0000u) + bc1.w + num[7]*inv;
    *(float4*)hp     = o0v;
    *(float4*)(hp+4) = o1v;
}

extern "C" void kernel_launch(void* const* d_in, const int* in_sizes, int n_in,
                              void* d_out, int out_size, void* d_ws, size_t ws_size,
                              hipStream_t stream) {
    const int*   trip   = (const int*)  d_in[0];
    const float* ent    = (const float*)d_in[1];
    const float* relE   = (const float*)d_in[2];
    const float* W_ent  = (const float*)d_in[3];
    const float* b_ent  = (const float*)d_in[4];
    const float* W_rel  = (const float*)d_in[5];
    const float* b_rel  = (const float*)d_in[6];
    const float* W_ent2 = (const float*)d_in[7];
    const float* b_ent2 = (const float*)d_in[8];
    const float* a_w    = (const float*)d_in[9];
    const float* a_b    = (const float*)d_in[10];
    float* h = (float*)d_out;

    // Workspace: ~57 MB total — stays under the proven-safe 57.6 MB.
    char* ws = (char*)d_ws;
    size_t o = 0;
    auto alloc = [&](size_t bytes) { size_t p = o; o += (bytes + 255) & ~(size_t)255; return p; };
    float*  WR     = (float*) (ws + alloc(128*128*4));
    ushort* WfTb   = (ushort*)(ws + alloc(256*128*2));
    float*  biasC  = (float*) (ws + alloc(128*4));
    ushort* RmB    = (ushort*)(ws + alloc((size_t)N_RELS_C*128*2));
    float*  sR     = (float*) (ws + alloc(N_RELS_C*4));
    float*  sConst = (float*) (ws + alloc(4));
    float*  sA     = (float*) (ws + alloc((size_t)N_NODES_C*4));
    float*  sB     = (float*) (ws + alloc((size_t)N_NODES_C*4));
    int*    deg    = (int*)   (ws + alloc((size_t)N_NODES_C*4));
    int*    off    = (int*)   (ws + alloc(((size_t)N_NODES_C+1)*4));
    int*    cursor = (int*)   (ws + alloc((size_t)N_NODES_C*4));
    int*    bsum   = (int*)   (ws + alloc(128*4));
    uint2*  kb     = (uint2*) (ws + alloc((size_t)N_EDGES_C*8));
    ushort* BnB    = (ushort*)(ws + alloc((size_t)N_PAD_C*128*2));
    ushort* AnB    = (ushort*)(ws + alloc((size_t)N_PAD_C*128*2));

    // 6 dispatches — verified round-3 pipeline; exp moved into k_edge_b.
    k_fuse_w<<<dim3(128,4), 128, 0, stream>>>(W_ent, W_rel, W_ent2, b_ent, b_rel, b_ent2,
                                              a_w, a_b, WR, WfTb, biasC, sConst, deg);
    k1_mega<<<GEMM0 + NBLK_GEMM, 512, 0, stream>>>(
        ent, WfTb, a_w, relE, WR, trip, AnB, BnB, RmB, sA, sB, sR, deg, N_NODES_C);
    int nb = (N_NODES_C + 1023)/1024;   // 98
    k_scan1<<<nb, 1024, 0, stream>>>(deg, off, bsum, N_NODES_C);
    k_scan23<<<nb, 1024, 0, stream>>>(off, cursor, bsum, N_NODES_C, nb, N_EDGES_C);
    k_edge_b<<<(N_EDGES_C+255)/256, 256, 0, stream>>>(trip, sA, sB, sR, sConst,
                                                      cursor, kb, N_EDGES_C);
    k_aggregate<<<(N_NODES_C+15)/16, 256, 0, stream>>>(off, kb, AnB, BnB, RmB, biasC,
                                                       h, N_NODES_C);
}